// Round 9
// baseline (302.639 us; speedup 1.0000x reference)
//
#include <hip/hip_runtime.h>
#include <hip/hip_bf16.h>

#define NN 50000
#define NE 800000
#define DD 128
#define BN_EPS 1e-5f
#define SCAN_G 98    // 98*512 = 50176 >= NN

typedef unsigned short ushort_t;
typedef unsigned int uint_t;
typedef __attribute__((ext_vector_type(8))) short short8v;   // 8 x bf16 (4 VGPR)
typedef __attribute__((ext_vector_type(4))) float f32x4;

__device__ __forceinline__ float b2f(ushort_t u) {
    union { uint_t i; float f; } v; v.i = ((uint_t)u) << 16; return v.f;
}
__device__ __forceinline__ ushort_t f2b(float f) {
    uint_t u = __float_as_uint(f);
    u += 0x7FFFu + ((u >> 16) & 1u);   // RNE
    return (ushort_t)(u >> 16);
}
__device__ __forceinline__ void atomAdd(float* p, float v) { unsafeAtomicAdd(p, v); }

// ---------- graph prep ----------
// epos[e] = position of edge e within its dst bucket; cnt ends as deg.
__global__ void epos_kernel(const int* __restrict__ dst, int* __restrict__ cnt,
                            int* __restrict__ epos) {
    int e = blockIdx.x * 256 + threadIdx.x;
    if (e < NE) epos[e] = atomicAdd(&cnt[dst[e]], 1);
}

// pass 1: per-block (512 elems) sums; also emits norm = rsqrt(max(deg,1))
__global__ __launch_bounds__(512) void scan_part(const int* __restrict__ deg,
                                                 int* __restrict__ part,
                                                 float* __restrict__ norm) {
    int i = blockIdx.x * 512 + threadIdx.x;
    int v = (i < NN) ? deg[i] : 0;
    if (i < NN) norm[i] = rsqrtf((float)max(v, 1));
    int s = v;
    #pragma unroll
    for (int k = 1; k < 64; k <<= 1) s += __shfl_xor(s, k);
    __shared__ int wsum[8];
    if ((threadIdx.x & 63) == 0) wsum[threadIdx.x >> 6] = s;
    __syncthreads();
    if (threadIdx.x == 0) {
        int t = 0;
        #pragma unroll
        for (int k = 0; k < 8; ++k) t += wsum[k];
        part[blockIdx.x] = t;
    }
}

// pass 2: block-local exclusive scan; base computed in-block from part[]
__global__ __launch_bounds__(512) void scan_final(const int* __restrict__ deg,
                                                  const int* __restrict__ part,
                                                  int* __restrict__ off) {
    __shared__ int wsum[8];
    __shared__ int sbase;
    int t = threadIdx.x;
    int lane = t & 63, wv = t >> 6;

    // base = sum part[0..bid-1]
    int p = (t < blockIdx.x && t < SCAN_G) ? part[t] : 0;
    #pragma unroll
    for (int s = 1; s < 64; s <<= 1) p += __shfl_xor(p, s);
    if (lane == 0) wsum[wv] = p;
    __syncthreads();
    if (t == 0) {
        int b = 0;
        #pragma unroll
        for (int k = 0; k < 8; ++k) b += wsum[k];
        sbase = b;
    }
    __syncthreads();

    int i = blockIdx.x * 512 + t;
    int v = (i < NN) ? deg[i] : 0;
    int incl = v;
    #pragma unroll
    for (int s = 1; s < 64; s <<= 1) {
        int u = __shfl_up(incl, s);
        if (lane >= s) incl += u;
    }
    __syncthreads();   // reuse wsum
    if (lane == 63) wsum[wv] = incl;
    __syncthreads();
    int woff = 0;
    for (int k = 0; k < wv; ++k) woff += wsum[k];
    int excl = sbase + woff + incl - v;
    if (i < NN) off[i] = excl;
    if (blockIdx.x == 0 && t == 0) off[NN] = NE;
}

// csr[off[dst]+epos] = (src, bits(norm[src])) — atomic-free scatter
__global__ void fill_kernel(const int* __restrict__ src, const int* __restrict__ dst,
                            const int* __restrict__ epos, const int* __restrict__ off,
                            const float* __restrict__ norm, int2* __restrict__ csr) {
    int e = blockIdx.x * 256 + threadIdx.x;
    if (e >= NE) return;
    int s = src[e];
    int p = off[dst[e]] + epos[e];
    csr[p] = make_int2(s, __float_as_int(norm[s]));
}

// ---------- conversions ----------
__global__ void f2bf_kernel(const float* __restrict__ in, ushort_t* __restrict__ out) {
    int i = blockIdx.x * 256 + threadIdx.x;   // per 4 elems
    if (i >= NN * DD / 4) return;
    float4 v = reinterpret_cast<const float4*>(in)[i];
    ushort4 o = { f2b(v.x), f2b(v.y), f2b(v.z), f2b(v.w) };
    reinterpret_cast<ushort4*>(out)[i] = o;
}

// WcT[d][k] (128 x 384 bf16): k<128: W1-W3; k<256: -W2; else 2*W3
__global__ void wct_kernel(const float* __restrict__ W1, const float* __restrict__ W2,
                           const float* __restrict__ W3, ushort_t* __restrict__ wcT) {
    int i = blockIdx.x * 256 + threadIdx.x;
    if (i >= DD * 384) return;
    int d = i / 384, k = i % 384;
    float v;
    if (k < 128)      v = W1[k * DD + d] - W3[k * DD + d];
    else if (k < 256) v = -W2[(k - 128) * DD + d];
    else              v = 2.0f * W3[(k - 256) * DD + d];
    wcT[i] = f2b(v);
}

// ---------- message passing (bf16 in, bf16 out), column-sliced ----------
// 4 column slices of 32 cols (3.2 MB each, fits one XCD L2).
// slice = (bid%8)>>1 -> steered to one XCD pair (bid%8 ~ XCD round-robin).
// wave per node; quarter-wave (16 lanes x uint = 64B) per edge; 2-deep unroll.
__global__ __launch_bounds__(256) void gather_slice(const ushort_t* __restrict__ x,
                                                    const float* __restrict__ norm,
                                                    const int* __restrict__ off,
                                                    const int2* __restrict__ csr,
                                                    ushort_t* __restrict__ out) {
    int bid = blockIdx.x;                        // 50000 blocks
    int slice = (bid & 7) >> 1;                  // 0..3
    int sbid = ((bid >> 3) << 1) | (bid & 1);    // 0..12499
    int wid = (sbid << 2) + (threadIdx.x >> 6);  // node id
    int lane = threadIdx.x & 63;
    int q = lane >> 4, l4 = lane & 15;
    int jb = off[wid], je = off[wid + 1];
    const uint_t* xs = reinterpret_cast<const uint_t*>(x) + (slice << 4) + l4;
    float a0 = 0.f, a1 = 0.f;
    for (int j = jb; j < je; j += 8) {
        int j0 = j + q, j1 = j + 4 + q;
        int2 c0 = (j0 < je) ? csr[j0] : make_int2(0, 0);
        int2 c1 = (j1 < je) ? csr[j1] : make_int2(0, 0);
        uint_t v0 = xs[(size_t)c0.x << 6];       // row stride = 64 uints
        uint_t v1 = xs[(size_t)c1.x << 6];
        float n0 = __int_as_float(c0.y), n1 = __int_as_float(c1.y);
        a0 = fmaf(n0, b2f((ushort_t)v0), a0);
        a1 = fmaf(n0, b2f((ushort_t)(v0 >> 16)), a1);
        a0 = fmaf(n1, b2f((ushort_t)v1), a0);
        a1 = fmaf(n1, b2f((ushort_t)(v1 >> 16)), a1);
    }
    a0 += __shfl_xor(a0, 16); a0 += __shfl_xor(a0, 32);
    a1 += __shfl_xor(a1, 16); a1 += __shfl_xor(a1, 32);
    if (q == 0) {
        float nd = norm[wid];
        uint_t o = (uint_t)f2b(nd * a0) | ((uint_t)f2b(nd * a1) << 16);
        reinterpret_cast<uint_t*>(out)[((size_t)wid << 6) + (slice << 4) + l4] = o;
    }
}

// ---------- MFMA GEMM + BN partials ----------
__global__ __launch_bounds__(256) void gemm_bn(
    const ushort_t* __restrict__ feat_bf, const ushort_t* __restrict__ ax_bf,
    const ushort_t* __restrict__ ax2_bf, const ushort_t* __restrict__ wcT,
    const float* __restrict__ bias, const float* __restrict__ snorm,
    ushort_t* __restrict__ t_out, float* __restrict__ gsums, float* __restrict__ gsq)
{
    __shared__ ushort_t As[64 * 128];    // 16 KB, XOR-swizzled
    __shared__ ushort_t Bs[128 * 128];   // 32 KB, XOR-swizzled
    int tid = threadIdx.x;
    int w = tid >> 6, lane = tid & 63;
    int row0 = blockIdx.x * 64;

    f32x4 acc[8] = {};

    #pragma unroll
    for (int kt = 0; kt < 3; ++kt) {
        const ushort_t* S = (kt == 0) ? feat_bf : (kt == 1) ? ax_bf : ax2_bf;
        __syncthreads();
        {
            int r = tid >> 2, q = tid & 3;
            int grow = min(row0 + r, NN - 1);
            const char* gsrc = (const char*)(S + grow * DD);
            char* dbase = (char*)As + r * 256;
            int sw = (r & 7) << 4;
            #pragma unroll
            for (int c = 0; c < 4; ++c) {
                int cb = (q * 4 + c) * 16;
                *(short8v*)(dbase + (cb ^ sw)) = *(const short8v*)(gsrc + cb);
            }
        }
        {
            int cidx = tid >> 1, hh = tid & 1;
            const char* gsrc = (const char*)(wcT + cidx * 384 + kt * 128);
            char* dbase = (char*)Bs + cidx * 256;
            int sw = (cidx & 7) << 4;
            #pragma unroll
            for (int c = 0; c < 8; ++c) {
                int cb = (hh * 8 + c) * 16;
                *(short8v*)(dbase + (cb ^ sw)) = *(const short8v*)(gsrc + cb);
            }
        }
        __syncthreads();
        int arow = w * 16 + (lane & 15);
        int asw = (arow & 7) << 4;
        #pragma unroll
        for (int ks = 0; ks < 4; ++ks) {
            int kb = ks * 64 + ((lane >> 4) << 4);
            short8v a = *(const short8v*)((const char*)As + arow * 256 + (kb ^ asw));
            #pragma unroll
            for (int cf = 0; cf < 8; ++cf) {
                int col = cf * 16 + (lane & 15);
                short8v b = *(const short8v*)((const char*)Bs + col * 256 + (kb ^ ((col & 7) << 4)));
                acc[cf] = __builtin_amdgcn_mfma_f32_16x16x32_bf16(a, b, acc[cf], 0, 0, 0);
            }
        }
    }

    int q = lane >> 4, c0 = lane & 15;
    int rbase = row0 + w * 16 + q * 4;
    float sn[4];
    #pragma unroll
    for (int i = 0; i < 4; ++i) sn[i] = (rbase + i < NN) ? snorm[rbase + i] : 0.f;

    float s1[8], s2[8];
    #pragma unroll
    for (int cf = 0; cf < 8; ++cf) {
        s1[cf] = 0.f; s2[cf] = 0.f;
        int col = cf * 16 + c0;
        float bc = bias[col];
        #pragma unroll
        for (int i = 0; i < 4; ++i) {
            int row = rbase + i;
            if (row < NN) {
                float t = (acc[cf][i] + bc) * sn[i];
                t_out[row * DD + col] = f2b(t);
                s1[cf] += t; s2[cf] += t * t;
            }
        }
    }
    #pragma unroll
    for (int cf = 0; cf < 8; ++cf) {
        s1[cf] += __shfl_xor(s1[cf], 16); s1[cf] += __shfl_xor(s1[cf], 32);
        s2[cf] += __shfl_xor(s2[cf], 16); s2[cf] += __shfl_xor(s2[cf], 32);
    }
    if (q == 0) {
        int slot = (blockIdx.x & 31) * DD;
        #pragma unroll
        for (int cf = 0; cf < 8; ++cf) {
            atomAdd(&gsums[slot + cf * 16 + c0], s1[cf]);
            atomAdd(&gsq[slot + cf * 16 + c0], s2[cf]);
        }
    }
}

__global__ void bn_finalize(const float* __restrict__ gsums, const float* __restrict__ gsq,
                            const float* __restrict__ gamma,
                            const float* __restrict__ beta,
                            float* __restrict__ scale, float* __restrict__ shift) {
    int d = threadIdx.x;  // 128
    float s1 = 0.f, s2 = 0.f;
    for (int c = 0; c < 32; ++c) { s1 += gsums[c * DD + d]; s2 += gsq[c * DD + d]; }
    float mean = s1 / (float)NN;
    float var  = s2 / (float)NN - mean * mean;
    float sc = gamma[d] * rsqrtf(var + BN_EPS);
    scale[d] = sc;
    shift[d] = beta[d] - mean * sc;
}

// out = feat_bf + relu(t*scale + shift)   (both bf16 inputs, f32 out)
__global__ void epilogue(const ushort_t* __restrict__ t, const ushort_t* __restrict__ featb,
                         const float* __restrict__ scale, const float* __restrict__ shift,
                         float* __restrict__ out) {
    int i = blockIdx.x * 256 + threadIdx.x;
    if (i >= NN * DD / 4) return;
    int d0 = (i << 2) & 127;
    ushort4 tv = reinterpret_cast<const ushort4*>(t)[i];
    ushort4 fv = reinterpret_cast<const ushort4*>(featb)[i];
    float4 o;
    o.x = b2f(fv.x) + fmaxf(b2f(tv.x) * scale[d0 + 0] + shift[d0 + 0], 0.f);
    o.y = b2f(fv.y) + fmaxf(b2f(tv.y) * scale[d0 + 1] + shift[d0 + 1], 0.f);
    o.z = b2f(fv.z) + fmaxf(b2f(tv.z) * scale[d0 + 2] + shift[d0 + 2], 0.f);
    o.w = b2f(fv.w) + fmaxf(b2f(tv.w) * scale[d0 + 3] + shift[d0 + 3], 0.f);
    reinterpret_cast<float4*>(out)[i] = o;
}

extern "C" void kernel_launch(void* const* d_in, const int* in_sizes, int n_in,
                              void* d_out, int out_size, void* d_ws, size_t ws_size,
                              hipStream_t stream) {
    const float* feat  = (const float*)d_in[0];
    const float* snorm = (const float*)d_in[1];
    const float* W1    = (const float*)d_in[2];
    const float* W2    = (const float*)d_in[3];
    const float* W3    = (const float*)d_in[4];
    const float* bias  = (const float*)d_in[5];
    const float* gamma = (const float*)d_in[6];
    const float* beta  = (const float*)d_in[7];
    const int* esrc = (const int*)d_in[8];
    const int* edst = (const int*)d_in[9];
    float* out = (float*)d_out;

    char* ws = (char*)d_ws;
    ushort_t* t_bf    = (ushort_t*)(ws);                 // 12,800,000 (gemm output)
    int*      epos    = (int*)     (ws);                 //  3,200,000 ALIAS of t_bf
                                                         //  (epos dead before gemm_bn runs)
    ushort_t* feat_bf = (ushort_t*)(ws + 12800000);      // 12,800,000
    ushort_t* ax_bf   = (ushort_t*)(ws + 25600000);      // 12,800,000
    ushort_t* ax2_bf  = (ushort_t*)(ws + 38400000);      // 12,800,000
    int2*     csr     = (int2*)    (ws + 51200000);      //  6,400,000 (src, norm bits)
    float*    norm    = (float*)   (ws + 57600000);      //    200,000
    int*      cnt     = (int*)     (ws + 57800000);      //    200,000 (-> deg)
    float*    gsums   = (float*)   (ws + 58000000);      //     16,384
    float*    gsq     = (float*)   (ws + 58016384);      //     16,384
    int*      off     = (int*)     (ws + 58032768);      //    200,064
    int*      part    = (int*)     (ws + 58232832);      //        512
    float*    scale   = (float*)   (ws + 58233856);      //        512
    float*    shift   = (float*)   (ws + 58234368);      //        512
    ushort_t* wcT     = (ushort_t*)(ws + 58234880);      //     98,304 (end 58,333,184)

    hipMemsetAsync(ws + 57800000, 0, 232768, stream);    // cnt, gsums, gsq

    epos_kernel<<<3125, 256, 0, stream>>>(edst, cnt, epos);
    scan_part  <<<SCAN_G, 512, 0, stream>>>(cnt, part, norm);
    scan_final <<<SCAN_G, 512, 0, stream>>>(cnt, part, off);
    fill_kernel<<<3125, 256, 0, stream>>>(esrc, edst, epos, off, norm, csr);

    f2bf_kernel<<<6250, 256, 0, stream>>>(feat, feat_bf);
    wct_kernel <<<192,  256, 0, stream>>>(W1, W2, W3, wcT);

    gather_slice<<<50000, 256, 0, stream>>>(feat_bf, norm, off, csr, ax_bf);
    gather_slice<<<50000, 256, 0, stream>>>(ax_bf,   norm, off, csr, ax2_bf);

    gemm_bn<<<782, 256, 0, stream>>>(feat_bf, ax_bf, ax2_bf, wcT, bias, snorm,
                                     t_bf, gsums, gsq);
    bn_finalize<<<1, 128, 0, stream>>>(gsums, gsq, gamma, beta, scale, shift);
    epilogue   <<<6250, 256, 0, stream>>>(t_bf, feat_bf, scale, shift, out);
}

// Round 10
// 193.050 us; speedup vs baseline: 1.5677x; 1.5677x over previous
//
#include <hip/hip_runtime.h>
#include <hip/hip_bf16.h>

#define NN 50000
#define NE 800000
#define DD 128
#define BN_EPS 1e-5f
#define SCAN_G 98    // 98*512 = 50176 >= NN

typedef unsigned short ushort_t;
typedef unsigned int uint_t;
typedef __attribute__((ext_vector_type(8))) short short8v;   // 8 x bf16 (4 VGPR)
typedef __attribute__((ext_vector_type(4))) float f32x4;

__device__ __forceinline__ float b2f(ushort_t u) {
    union { uint_t i; float f; } v; v.i = ((uint_t)u) << 16; return v.f;
}
__device__ __forceinline__ ushort_t f2b(float f) {
    uint_t u = __float_as_uint(f);
    u += 0x7FFFu + ((u >> 16) & 1u);   // RNE
    return (ushort_t)(u >> 16);
}
__device__ __forceinline__ void atomAdd(float* p, float v) { unsafeAtomicAdd(p, v); }
// nontemporal CSR load (streamed once; keep x rows resident in L2)
__device__ __forceinline__ int2 ldnt2(const int2* p) {
    unsigned long long v =
        __builtin_nontemporal_load(reinterpret_cast<const unsigned long long*>(p));
    int2 r; r.x = (int)(v & 0xFFFFFFFFull); r.y = (int)(v >> 32); return r;
}

// ---------- graph prep ----------
// epos[e] = position of edge e within its dst bucket; cnt ends as deg.
__global__ void epos_kernel(const int* __restrict__ dst, int* __restrict__ cnt,
                            int* __restrict__ epos) {
    int e = blockIdx.x * 256 + threadIdx.x;
    if (e < NE) epos[e] = atomicAdd(&cnt[dst[e]], 1);
}

// pass 1: per-block (512 elems) sums; also emits norm = rsqrt(max(deg,1))
__global__ __launch_bounds__(512) void scan_part(const int* __restrict__ deg,
                                                 int* __restrict__ part,
                                                 float* __restrict__ norm) {
    int i = blockIdx.x * 512 + threadIdx.x;
    int v = (i < NN) ? deg[i] : 0;
    if (i < NN) norm[i] = rsqrtf((float)max(v, 1));
    int s = v;
    #pragma unroll
    for (int k = 1; k < 64; k <<= 1) s += __shfl_xor(s, k);
    __shared__ int wsum[8];
    if ((threadIdx.x & 63) == 0) wsum[threadIdx.x >> 6] = s;
    __syncthreads();
    if (threadIdx.x == 0) {
        int t = 0;
        #pragma unroll
        for (int k = 0; k < 8; ++k) t += wsum[k];
        part[blockIdx.x] = t;
    }
}

// pass 2: block-local exclusive scan; base computed in-block from part[]
__global__ __launch_bounds__(512) void scan_final(const int* __restrict__ deg,
                                                  const int* __restrict__ part,
                                                  int* __restrict__ off) {
    __shared__ int wsum[8];
    __shared__ int sbase;
    int t = threadIdx.x;
    int lane = t & 63, wv = t >> 6;

    int p = (t < blockIdx.x && t < SCAN_G) ? part[t] : 0;
    #pragma unroll
    for (int s = 1; s < 64; s <<= 1) p += __shfl_xor(p, s);
    if (lane == 0) wsum[wv] = p;
    __syncthreads();
    if (t == 0) {
        int b = 0;
        #pragma unroll
        for (int k = 0; k < 8; ++k) b += wsum[k];
        sbase = b;
    }
    __syncthreads();

    int i = blockIdx.x * 512 + t;
    int v = (i < NN) ? deg[i] : 0;
    int incl = v;
    #pragma unroll
    for (int s = 1; s < 64; s <<= 1) {
        int u = __shfl_up(incl, s);
        if (lane >= s) incl += u;
    }
    __syncthreads();
    if (lane == 63) wsum[wv] = incl;
    __syncthreads();
    int woff = 0;
    for (int k = 0; k < wv; ++k) woff += wsum[k];
    int excl = sbase + woff + incl - v;
    if (i < NN) off[i] = excl;
    if (blockIdx.x == 0 && t == 0) off[NN] = NE;
}

// csr[off[dst]+epos] = (src, bits(norm[src])) — atomic-free scatter
__global__ void fill_kernel(const int* __restrict__ src, const int* __restrict__ dst,
                            const int* __restrict__ epos, const int* __restrict__ off,
                            const float* __restrict__ norm, int2* __restrict__ csr) {
    int e = blockIdx.x * 256 + threadIdx.x;
    if (e >= NE) return;
    int s = src[e];
    int p = off[dst[e]] + epos[e];
    csr[p] = make_int2(s, __float_as_int(norm[s]));
}

// ---------- fused conversions: feat->bf16 and WcT build ----------
__global__ void prep_kernel(const float* __restrict__ feat, ushort_t* __restrict__ feat_bf,
                            const float* __restrict__ W1, const float* __restrict__ W2,
                            const float* __restrict__ W3, ushort_t* __restrict__ wcT) {
    int b = blockIdx.x;
    if (b < 6250) {
        int i = b * 256 + threadIdx.x;   // per 4 elems
        float4 v = reinterpret_cast<const float4*>(feat)[i];
        ushort4 o = { f2b(v.x), f2b(v.y), f2b(v.z), f2b(v.w) };
        reinterpret_cast<ushort4*>(feat_bf)[i] = o;
    } else {
        int i = (b - 6250) * 256 + threadIdx.x;
        if (i >= DD * 384) return;
        int d = i / 384, k = i % 384;
        float v;
        if (k < 128)      v = W1[k * DD + d] - W3[k * DD + d];
        else if (k < 256) v = -W2[(k - 128) * DD + d];
        else              v = 2.0f * W3[(k - 256) * DD + d];
        wcT[i] = f2b(v);
    }
}

// ---------- message passing (bf16 in, bf16 out) ----------
// wave per node; HALF-WAVE per edge (lane loads uint2 = 4 bf16 cols).
// 4-deep unroll per half => 8 independent row loads in flight per wave.
__global__ __launch_bounds__(256) void gather_bf(const ushort_t* __restrict__ x,
                                                 const float* __restrict__ norm,
                                                 const int* __restrict__ off,
                                                 const int2* __restrict__ csr,
                                                 ushort_t* __restrict__ out) {
    int wid = (blockIdx.x << 2) + (threadIdx.x >> 6);
    int lane = threadIdx.x & 63;
    int h = lane >> 5, l5 = lane & 31;
    int jb = off[wid], je = off[wid + 1];
    const uint2* xp = reinterpret_cast<const uint2*>(x);   // row = 32 x uint2
    float a0 = 0.f, a1 = 0.f, a2 = 0.f, a3 = 0.f;
    int j = jb;
    for (; j + 8 <= je; j += 8) {
        int e = j + (h << 2);
        int2 c0 = ldnt2(&csr[e + 0]);
        int2 c1 = ldnt2(&csr[e + 1]);
        int2 c2 = ldnt2(&csr[e + 2]);
        int2 c3 = ldnt2(&csr[e + 3]);
        uint2 v0 = xp[c0.x * 32 + l5];
        uint2 v1 = xp[c1.x * 32 + l5];
        uint2 v2 = xp[c2.x * 32 + l5];
        uint2 v3 = xp[c3.x * 32 + l5];
        float n0 = __int_as_float(c0.y), n1 = __int_as_float(c1.y);
        float n2 = __int_as_float(c2.y), n3 = __int_as_float(c3.y);
        a0 = fmaf(n0, b2f((ushort_t)v0.x), a0);
        a1 = fmaf(n0, b2f((ushort_t)(v0.x >> 16)), a1);
        a2 = fmaf(n0, b2f((ushort_t)v0.y), a2);
        a3 = fmaf(n0, b2f((ushort_t)(v0.y >> 16)), a3);
        a0 = fmaf(n1, b2f((ushort_t)v1.x), a0);
        a1 = fmaf(n1, b2f((ushort_t)(v1.x >> 16)), a1);
        a2 = fmaf(n1, b2f((ushort_t)v1.y), a2);
        a3 = fmaf(n1, b2f((ushort_t)(v1.y >> 16)), a3);
        a0 = fmaf(n2, b2f((ushort_t)v2.x), a0);
        a1 = fmaf(n2, b2f((ushort_t)(v2.x >> 16)), a1);
        a2 = fmaf(n2, b2f((ushort_t)v2.y), a2);
        a3 = fmaf(n2, b2f((ushort_t)(v2.y >> 16)), a3);
        a0 = fmaf(n3, b2f((ushort_t)v3.x), a0);
        a1 = fmaf(n3, b2f((ushort_t)(v3.x >> 16)), a1);
        a2 = fmaf(n3, b2f((ushort_t)v3.y), a2);
        a3 = fmaf(n3, b2f((ushort_t)(v3.y >> 16)), a3);
    }
    for (; j + 2 <= je; j += 2) {
        int2 c = ldnt2(&csr[j + h]);
        uint2 v = xp[c.x * 32 + l5];
        float n = __int_as_float(c.y);
        a0 = fmaf(n, b2f((ushort_t)v.x), a0);
        a1 = fmaf(n, b2f((ushort_t)(v.x >> 16)), a1);
        a2 = fmaf(n, b2f((ushort_t)v.y), a2);
        a3 = fmaf(n, b2f((ushort_t)(v.y >> 16)), a3);
    }
    if (j < je && h == 0) {
        int2 c = ldnt2(&csr[j]);
        uint2 v = xp[c.x * 32 + l5];
        float n = __int_as_float(c.y);
        a0 = fmaf(n, b2f((ushort_t)v.x), a0);
        a1 = fmaf(n, b2f((ushort_t)(v.x >> 16)), a1);
        a2 = fmaf(n, b2f((ushort_t)v.y), a2);
        a3 = fmaf(n, b2f((ushort_t)(v.y >> 16)), a3);
    }
    a0 += __shfl_xor(a0, 32);
    a1 += __shfl_xor(a1, 32);
    a2 += __shfl_xor(a2, 32);
    a3 += __shfl_xor(a3, 32);
    if (h == 0) {
        float nd = norm[wid];
        uint2 o;
        o.x = (uint_t)f2b(nd * a0) | ((uint_t)f2b(nd * a1) << 16);
        o.y = (uint_t)f2b(nd * a2) | ((uint_t)f2b(nd * a3) << 16);
        reinterpret_cast<uint2*>(out)[wid * 32 + l5] = o;
    }
}

// ---------- MFMA GEMM + BN partials ----------
// 128-row blocks, 4 waves; wave owns 32 rows x 128 cols (2 row-groups).
// B-fragment reads amortized over 2 MFMAs.
__global__ __launch_bounds__(256) void gemm_bn(
    const ushort_t* __restrict__ feat_bf, const ushort_t* __restrict__ ax_bf,
    const ushort_t* __restrict__ ax2_bf, const ushort_t* __restrict__ wcT,
    const float* __restrict__ bias, const float* __restrict__ snorm,
    ushort_t* __restrict__ t_out, float* __restrict__ gsums, float* __restrict__ gsq)
{
    __shared__ ushort_t As[128 * 128];   // 32 KB, XOR-swizzled
    __shared__ ushort_t Bs[128 * 128];   // 32 KB, XOR-swizzled
    int tid = threadIdx.x;
    int w = tid >> 6, lane = tid & 63;
    int row0 = blockIdx.x * 128;

    f32x4 acc[2][8] = {};

    #pragma unroll
    for (int kt = 0; kt < 3; ++kt) {
        const ushort_t* S = (kt == 0) ? feat_bf : (kt == 1) ? ax_bf : ax2_bf;
        __syncthreads();
        // stage A-tile: 128 rows x 128 k; thread covers 128 B (half row)
        {
            int r = tid >> 1, hh = tid & 1;
            int grow = min(row0 + r, NN - 1);
            const char* gsrc = (const char*)(S + grow * DD);
            char* dbase = (char*)As + r * 256;
            int sw = (r & 7) << 4;
            #pragma unroll
            for (int c = 0; c < 8; ++c) {
                int cb = hh * 128 + c * 16;
                *(short8v*)(dbase + (cb ^ sw)) = *(const short8v*)(gsrc + cb);
            }
        }
        // stage B^T slice: 128 cols x 128 k  (WcT row-major [128][384])
        {
            int cidx = tid >> 1, hh = tid & 1;
            const char* gsrc = (const char*)(wcT + cidx * 384 + kt * 128);
            char* dbase = (char*)Bs + cidx * 256;
            int sw = (cidx & 7) << 4;
            #pragma unroll
            for (int c = 0; c < 8; ++c) {
                int cb = hh * 128 + c * 16;
                *(short8v*)(dbase + (cb ^ sw)) = *(const short8v*)(gsrc + cb);
            }
        }
        __syncthreads();
        int l15 = lane & 15;
        int r0a = w * 32 + l15;
        int r1a = r0a + 16;
        #pragma unroll
        for (int ks = 0; ks < 4; ++ks) {
            int kb = ks * 64 + ((lane >> 4) << 4);
            short8v a0 = *(const short8v*)((const char*)As + r0a * 256 + (kb ^ ((r0a & 7) << 4)));
            short8v a1 = *(const short8v*)((const char*)As + r1a * 256 + (kb ^ ((r1a & 7) << 4)));
            #pragma unroll
            for (int cf = 0; cf < 8; ++cf) {
                int col = cf * 16 + l15;
                short8v b = *(const short8v*)((const char*)Bs + col * 256 + (kb ^ ((col & 7) << 4)));
                acc[0][cf] = __builtin_amdgcn_mfma_f32_16x16x32_bf16(a0, b, acc[0][cf], 0, 0, 0);
                acc[1][cf] = __builtin_amdgcn_mfma_f32_16x16x32_bf16(a1, b, acc[1][cf], 0, 0, 0);
            }
        }
    }

    int q = lane >> 4, c0 = lane & 15;
    float s1[8], s2[8];
    #pragma unroll
    for (int cf = 0; cf < 8; ++cf) { s1[cf] = 0.f; s2[cf] = 0.f; }

    #pragma unroll
    for (int g = 0; g < 2; ++g) {
        int rbase = row0 + w * 32 + g * 16 + q * 4;
        float sn[4];
        #pragma unroll
        for (int i = 0; i < 4; ++i) sn[i] = (rbase + i < NN) ? snorm[rbase + i] : 0.f;
        #pragma unroll
        for (int cf = 0; cf < 8; ++cf) {
            int col = cf * 16 + c0;
            float bc = bias[col];
            #pragma unroll
            for (int i = 0; i < 4; ++i) {
                int row = rbase + i;
                if (row < NN) {
                    float t = (acc[g][cf][i] + bc) * sn[i];
                    t_out[row * DD + col] = f2b(t);
                    s1[cf] += t; s2[cf] += t * t;
                }
            }
        }
    }
    #pragma unroll
    for (int cf = 0; cf < 8; ++cf) {
        s1[cf] += __shfl_xor(s1[cf], 16); s1[cf] += __shfl_xor(s1[cf], 32);
        s2[cf] += __shfl_xor(s2[cf], 16); s2[cf] += __shfl_xor(s2[cf], 32);
    }
    if (q == 0) {
        int slot = (blockIdx.x & 31) * DD;
        #pragma unroll
        for (int cf = 0; cf < 8; ++cf) {
            atomAdd(&gsums[slot + cf * 16 + c0], s1[cf]);
            atomAdd(&gsq[slot + cf * 16 + c0], s2[cf]);
        }
    }
}

__global__ void bn_finalize(const float* __restrict__ gsums, const float* __restrict__ gsq,
                            const float* __restrict__ gamma,
                            const float* __restrict__ beta,
                            float* __restrict__ scale, float* __restrict__ shift) {
    int d = threadIdx.x;  // 128
    float s1 = 0.f, s2 = 0.f;
    for (int c = 0; c < 32; ++c) { s1 += gsums[c * DD + d]; s2 += gsq[c * DD + d]; }
    float mean = s1 / (float)NN;
    float var  = s2 / (float)NN - mean * mean;
    float sc = gamma[d] * rsqrtf(var + BN_EPS);
    scale[d] = sc;
    shift[d] = beta[d] - mean * sc;
}

// out = feat_bf + relu(t*scale + shift)   (both bf16 inputs, f32 out)
__global__ void epilogue(const ushort_t* __restrict__ t, const ushort_t* __restrict__ featb,
                         const float* __restrict__ scale, const float* __restrict__ shift,
                         float* __restrict__ out) {
    int i = blockIdx.x * 256 + threadIdx.x;
    if (i >= NN * DD / 4) return;
    int d0 = (i << 2) & 127;
    ushort4 tv = reinterpret_cast<const ushort4*>(t)[i];
    ushort4 fv = reinterpret_cast<const ushort4*>(featb)[i];
    float4 o;
    o.x = b2f(fv.x) + fmaxf(b2f(tv.x) * scale[d0 + 0] + shift[d0 + 0], 0.f);
    o.y = b2f(fv.y) + fmaxf(b2f(tv.y) * scale[d0 + 1] + shift[d0 + 1], 0.f);
    o.z = b2f(fv.z) + fmaxf(b2f(tv.z) * scale[d0 + 2] + shift[d0 + 2], 0.f);
    o.w = b2f(fv.w) + fmaxf(b2f(tv.w) * scale[d0 + 3] + shift[d0 + 3], 0.f);
    reinterpret_cast<float4*>(out)[i] = o;
}

extern "C" void kernel_launch(void* const* d_in, const int* in_sizes, int n_in,
                              void* d_out, int out_size, void* d_ws, size_t ws_size,
                              hipStream_t stream) {
    const float* feat  = (const float*)d_in[0];
    const float* snorm = (const float*)d_in[1];
    const float* W1    = (const float*)d_in[2];
    const float* W2    = (const float*)d_in[3];
    const float* W3    = (const float*)d_in[4];
    const float* bias  = (const float*)d_in[5];
    const float* gamma = (const float*)d_in[6];
    const float* beta  = (const float*)d_in[7];
    const int* esrc = (const int*)d_in[8];
    const int* edst = (const int*)d_in[9];
    float* out = (float*)d_out;

    char* ws = (char*)d_ws;
    ushort_t* t_bf    = (ushort_t*)(ws);                 // 12,800,000 (gemm output)
    int*      epos    = (int*)     (ws);                 //  3,200,000 ALIAS of t_bf
                                                         //  (epos dead before gemm_bn runs)
    ushort_t* feat_bf = (ushort_t*)(ws + 12800000);      // 12,800,000
    ushort_t* ax_bf   = (ushort_t*)(ws + 25600000);      // 12,800,000
    ushort_t* ax2_bf  = (ushort_t*)(ws + 38400000);      // 12,800,000
    int2*     csr     = (int2*)    (ws + 51200000);      //  6,400,000 (src, norm bits)
    float*    norm    = (float*)   (ws + 57600000);      //    200,000
    int*      cnt     = (int*)     (ws + 57800000);      //    200,000 (-> deg)
    float*    gsums   = (float*)   (ws + 58000000);      //     16,384
    float*    gsq     = (float*)   (ws + 58016384);      //     16,384
    int*      off     = (int*)     (ws + 58032768);      //    200,064
    int*      part    = (int*)     (ws + 58232832);      //        512
    float*    scale   = (float*)   (ws + 58233856);      //        512
    float*    shift   = (float*)   (ws + 58234368);      //        512
    ushort_t* wcT     = (ushort_t*)(ws + 58234880);      //     98,304 (end 58,333,184)

    hipMemsetAsync(ws + 57800000, 0, 232768, stream);    // cnt, gsums, gsq

    epos_kernel<<<3125, 256, 0, stream>>>(edst, cnt, epos);
    scan_part  <<<SCAN_G, 512, 0, stream>>>(cnt, part, norm);
    scan_final <<<SCAN_G, 512, 0, stream>>>(cnt, part, off);
    fill_kernel<<<3125, 256, 0, stream>>>(esrc, edst, epos, off, norm, csr);

    prep_kernel<<<6442, 256, 0, stream>>>(feat, feat_bf, W1, W2, W3, wcT);

    gather_bf<<<12500, 256, 0, stream>>>(feat_bf, norm, off, csr, ax_bf);
    gather_bf<<<12500, 256, 0, stream>>>(ax_bf,   norm, off, csr, ax2_bf);

    gemm_bn<<<391, 256, 0, stream>>>(feat_bf, ax_bf, ax2_bf, wcT, bias, snorm,
                                     t_bf, gsums, gsq);
    bn_finalize<<<1, 128, 0, stream>>>(gsums, gsq, gamma, beta, scale, shift);
    epilogue   <<<6250, 256, 0, stream>>>(t_bf, feat_bf, scale, shift, out);
}

// Round 11
// 175.607 us; speedup vs baseline: 1.7234x; 1.0993x over previous
//
#include <hip/hip_runtime.h>
#include <hip/hip_bf16.h>

#define NN 50000
#define NE 800000
#define DD 128
#define BN_EPS 1e-5f
#define SCAN_G 98    // 98*512 = 50176 >= NN

typedef unsigned short ushort_t;
typedef unsigned int uint_t;
typedef __attribute__((ext_vector_type(8))) short short8v;   // 8 x bf16 (4 VGPR)
typedef __attribute__((ext_vector_type(4))) float f32x4;

__device__ __forceinline__ float b2f(ushort_t u) {
    union { uint_t i; float f; } v; v.i = ((uint_t)u) << 16; return v.f;
}
__device__ __forceinline__ ushort_t f2b(float f) {
    uint_t u = __float_as_uint(f);
    u += 0x7FFFu + ((u >> 16) & 1u);   // RNE
    return (ushort_t)(u >> 16);
}
__device__ __forceinline__ void atomAdd(float* p, float v) { unsafeAtomicAdd(p, v); }

// ---------- graph prep ----------
// epos[e] = position of edge e within its dst bucket; cnt ends as deg.
__global__ void epos_kernel(const int* __restrict__ dst, int* __restrict__ cnt,
                            int* __restrict__ epos) {
    int e = blockIdx.x * 256 + threadIdx.x;
    if (e < NE) epos[e] = atomicAdd(&cnt[dst[e]], 1);
}

// pass 1: per-block (512 elems) sums; also emits norm = rsqrt(max(deg,1))
__global__ __launch_bounds__(512) void scan_part(const int* __restrict__ deg,
                                                 int* __restrict__ part,
                                                 float* __restrict__ norm) {
    int i = blockIdx.x * 512 + threadIdx.x;
    int v = (i < NN) ? deg[i] : 0;
    if (i < NN) norm[i] = rsqrtf((float)max(v, 1));
    int s = v;
    #pragma unroll
    for (int k = 1; k < 64; k <<= 1) s += __shfl_xor(s, k);
    __shared__ int wsum[8];
    if ((threadIdx.x & 63) == 0) wsum[threadIdx.x >> 6] = s;
    __syncthreads();
    if (threadIdx.x == 0) {
        int t = 0;
        #pragma unroll
        for (int k = 0; k < 8; ++k) t += wsum[k];
        part[blockIdx.x] = t;
    }
}

// pass 2: block-local exclusive scan; base computed in-block from part[]
__global__ __launch_bounds__(512) void scan_final(const int* __restrict__ deg,
                                                  const int* __restrict__ part,
                                                  int* __restrict__ off) {
    __shared__ int wsum[8];
    __shared__ int sbase;
    int t = threadIdx.x;
    int lane = t & 63, wv = t >> 6;

    int p = (t < blockIdx.x && t < SCAN_G) ? part[t] : 0;
    #pragma unroll
    for (int s = 1; s < 64; s <<= 1) p += __shfl_xor(p, s);
    if (lane == 0) wsum[wv] = p;
    __syncthreads();
    if (t == 0) {
        int b = 0;
        #pragma unroll
        for (int k = 0; k < 8; ++k) b += wsum[k];
        sbase = b;
    }
    __syncthreads();

    int i = blockIdx.x * 512 + t;
    int v = (i < NN) ? deg[i] : 0;
    int incl = v;
    #pragma unroll
    for (int s = 1; s < 64; s <<= 1) {
        int u = __shfl_up(incl, s);
        if (lane >= s) incl += u;
    }
    __syncthreads();
    if (lane == 63) wsum[wv] = incl;
    __syncthreads();
    int woff = 0;
    for (int k = 0; k < wv; ++k) woff += wsum[k];
    int excl = sbase + woff + incl - v;
    if (i < NN) off[i] = excl;
    if (blockIdx.x == 0 && t == 0) off[NN] = NE;
}

// csr[off[dst]+epos] = (src, bits(norm[src])) — atomic-free scatter
__global__ void fill_kernel(const int* __restrict__ src, const int* __restrict__ dst,
                            const int* __restrict__ epos, const int* __restrict__ off,
                            const float* __restrict__ norm, int2* __restrict__ csr) {
    int e = blockIdx.x * 256 + threadIdx.x;
    if (e >= NE) return;
    int s = src[e];
    int p = off[dst[e]] + epos[e];
    csr[p] = make_int2(s, __float_as_int(norm[s]));
}

// ---------- fused conversions: feat->bf16 and WcT build ----------
__global__ void prep_kernel(const float* __restrict__ feat, ushort_t* __restrict__ feat_bf,
                            const float* __restrict__ W1, const float* __restrict__ W2,
                            const float* __restrict__ W3, ushort_t* __restrict__ wcT) {
    int b = blockIdx.x;
    if (b < 6250) {
        int i = b * 256 + threadIdx.x;   // per 4 elems
        float4 v = reinterpret_cast<const float4*>(feat)[i];
        ushort4 o = { f2b(v.x), f2b(v.y), f2b(v.z), f2b(v.w) };
        reinterpret_cast<ushort4*>(feat_bf)[i] = o;
    } else {
        int i = (b - 6250) * 256 + threadIdx.x;
        if (i >= DD * 384) return;
        int d = i / 384, k = i % 384;
        float v;
        if (k < 128)      v = W1[k * DD + d] - W3[k * DD + d];
        else if (k < 256) v = -W2[(k - 128) * DD + d];
        else              v = 2.0f * W3[(k - 256) * DD + d];
        wcT[i] = f2b(v);
    }
}

// ---------- message passing (bf16 in, bf16 out) ----------
// wave per node; QUARTER-WAVE per edge (lane loads uint4 = 8 bf16 cols).
// 4 edges/instruction x 4-deep unroll => 16 independent row loads in flight.
__global__ __launch_bounds__(256) void gather_bf(const ushort_t* __restrict__ x,
                                                 const float* __restrict__ norm,
                                                 const int* __restrict__ off,
                                                 const int2* __restrict__ csr,
                                                 ushort_t* __restrict__ out) {
    int wid = (blockIdx.x << 2) + (threadIdx.x >> 6);
    int lane = threadIdx.x & 63;
    int q = lane >> 4, l4 = lane & 15;
    int jb = off[wid], je = off[wid + 1];
    const uint4* xp = reinterpret_cast<const uint4*>(x);   // row = 16 x uint4
    float a0 = 0.f, a1 = 0.f, a2 = 0.f, a3 = 0.f;
    float a4 = 0.f, a5 = 0.f, a6 = 0.f, a7 = 0.f;

#define ACC(cc, vv)                                                  \
    {                                                                \
        float n_ = __int_as_float(cc.y);                             \
        a0 = fmaf(n_, b2f((ushort_t)vv.x), a0);                      \
        a1 = fmaf(n_, b2f((ushort_t)(vv.x >> 16)), a1);              \
        a2 = fmaf(n_, b2f((ushort_t)vv.y), a2);                      \
        a3 = fmaf(n_, b2f((ushort_t)(vv.y >> 16)), a3);              \
        a4 = fmaf(n_, b2f((ushort_t)vv.z), a4);                      \
        a5 = fmaf(n_, b2f((ushort_t)(vv.z >> 16)), a5);              \
        a6 = fmaf(n_, b2f((ushort_t)vv.w), a6);                      \
        a7 = fmaf(n_, b2f((ushort_t)(vv.w >> 16)), a7);              \
    }

    int j = jb;
    for (; j + 16 <= je; j += 16) {
        int2 c0 = csr[j + q];
        int2 c1 = csr[j + 4 + q];
        int2 c2 = csr[j + 8 + q];
        int2 c3 = csr[j + 12 + q];
        uint4 v0 = xp[(size_t)c0.x * 16 + l4];
        uint4 v1 = xp[(size_t)c1.x * 16 + l4];
        uint4 v2 = xp[(size_t)c2.x * 16 + l4];
        uint4 v3 = xp[(size_t)c3.x * 16 + l4];
        ACC(c0, v0); ACC(c1, v1); ACC(c2, v2); ACC(c3, v3);
    }
    for (; j < je; j += 4) {
        int jj = j + q;
        int2 c = (jj < je) ? csr[jj] : make_int2(0, 0);
        uint4 v = xp[(size_t)c.x * 16 + l4];
        ACC(c, v);
    }
#undef ACC

    a0 += __shfl_xor(a0, 16); a0 += __shfl_xor(a0, 32);
    a1 += __shfl_xor(a1, 16); a1 += __shfl_xor(a1, 32);
    a2 += __shfl_xor(a2, 16); a2 += __shfl_xor(a2, 32);
    a3 += __shfl_xor(a3, 16); a3 += __shfl_xor(a3, 32);
    a4 += __shfl_xor(a4, 16); a4 += __shfl_xor(a4, 32);
    a5 += __shfl_xor(a5, 16); a5 += __shfl_xor(a5, 32);
    a6 += __shfl_xor(a6, 16); a6 += __shfl_xor(a6, 32);
    a7 += __shfl_xor(a7, 16); a7 += __shfl_xor(a7, 32);
    if (q == 0) {
        float nd = norm[wid];
        uint4 o;
        o.x = (uint_t)f2b(nd * a0) | ((uint_t)f2b(nd * a1) << 16);
        o.y = (uint_t)f2b(nd * a2) | ((uint_t)f2b(nd * a3) << 16);
        o.z = (uint_t)f2b(nd * a4) | ((uint_t)f2b(nd * a5) << 16);
        o.w = (uint_t)f2b(nd * a6) | ((uint_t)f2b(nd * a7) << 16);
        reinterpret_cast<uint4*>(out)[(size_t)wid * 16 + l4] = o;
    }
}

// ---------- MFMA GEMM + BN partials ----------
// 128-row blocks, 4 waves; wave owns 32 rows x 128 cols (2 row-groups).
__global__ __launch_bounds__(256) void gemm_bn(
    const ushort_t* __restrict__ feat_bf, const ushort_t* __restrict__ ax_bf,
    const ushort_t* __restrict__ ax2_bf, const ushort_t* __restrict__ wcT,
    const float* __restrict__ bias, const float* __restrict__ snorm,
    ushort_t* __restrict__ t_out, float* __restrict__ gsums, float* __restrict__ gsq)
{
    __shared__ ushort_t As[128 * 128];   // 32 KB, XOR-swizzled
    __shared__ ushort_t Bs[128 * 128];   // 32 KB, XOR-swizzled
    int tid = threadIdx.x;
    int w = tid >> 6, lane = tid & 63;
    int row0 = blockIdx.x * 128;

    f32x4 acc[2][8] = {};

    #pragma unroll
    for (int kt = 0; kt < 3; ++kt) {
        const ushort_t* S = (kt == 0) ? feat_bf : (kt == 1) ? ax_bf : ax2_bf;
        __syncthreads();
        {
            int r = tid >> 1, hh = tid & 1;
            int grow = min(row0 + r, NN - 1);
            const char* gsrc = (const char*)(S + grow * DD);
            char* dbase = (char*)As + r * 256;
            int sw = (r & 7) << 4;
            #pragma unroll
            for (int c = 0; c < 8; ++c) {
                int cb = hh * 128 + c * 16;
                *(short8v*)(dbase + (cb ^ sw)) = *(const short8v*)(gsrc + cb);
            }
        }
        {
            int cidx = tid >> 1, hh = tid & 1;
            const char* gsrc = (const char*)(wcT + cidx * 384 + kt * 128);
            char* dbase = (char*)Bs + cidx * 256;
            int sw = (cidx & 7) << 4;
            #pragma unroll
            for (int c = 0; c < 8; ++c) {
                int cb = hh * 128 + c * 16;
                *(short8v*)(dbase + (cb ^ sw)) = *(const short8v*)(gsrc + cb);
            }
        }
        __syncthreads();
        int l15 = lane & 15;
        int r0a = w * 32 + l15;
        int r1a = r0a + 16;
        #pragma unroll
        for (int ks = 0; ks < 4; ++ks) {
            int kb = ks * 64 + ((lane >> 4) << 4);
            short8v a0 = *(const short8v*)((const char*)As + r0a * 256 + (kb ^ ((r0a & 7) << 4)));
            short8v a1 = *(const short8v*)((const char*)As + r1a * 256 + (kb ^ ((r1a & 7) << 4)));
            #pragma unroll
            for (int cf = 0; cf < 8; ++cf) {
                int col = cf * 16 + l15;
                short8v b = *(const short8v*)((const char*)Bs + col * 256 + (kb ^ ((col & 7) << 4)));
                acc[0][cf] = __builtin_amdgcn_mfma_f32_16x16x32_bf16(a0, b, acc[0][cf], 0, 0, 0);
                acc[1][cf] = __builtin_amdgcn_mfma_f32_16x16x32_bf16(a1, b, acc[1][cf], 0, 0, 0);
            }
        }
    }

    int q = lane >> 4, c0 = lane & 15;
    float s1[8], s2[8];
    #pragma unroll
    for (int cf = 0; cf < 8; ++cf) { s1[cf] = 0.f; s2[cf] = 0.f; }

    #pragma unroll
    for (int g = 0; g < 2; ++g) {
        int rbase = row0 + w * 32 + g * 16 + q * 4;
        float sn[4];
        #pragma unroll
        for (int i = 0; i < 4; ++i) sn[i] = (rbase + i < NN) ? snorm[rbase + i] : 0.f;
        #pragma unroll
        for (int cf = 0; cf < 8; ++cf) {
            int col = cf * 16 + c0;
            float bc = bias[col];
            #pragma unroll
            for (int i = 0; i < 4; ++i) {
                int row = rbase + i;
                if (row < NN) {
                    float t = (acc[g][cf][i] + bc) * sn[i];
                    t_out[row * DD + col] = f2b(t);
                    s1[cf] += t; s2[cf] += t * t;
                }
            }
        }
    }
    #pragma unroll
    for (int cf = 0; cf < 8; ++cf) {
        s1[cf] += __shfl_xor(s1[cf], 16); s1[cf] += __shfl_xor(s1[cf], 32);
        s2[cf] += __shfl_xor(s2[cf], 16); s2[cf] += __shfl_xor(s2[cf], 32);
    }
    if (q == 0) {
        int slot = (blockIdx.x & 31) * DD;
        #pragma unroll
        for (int cf = 0; cf < 8; ++cf) {
            atomAdd(&gsums[slot + cf * 16 + c0], s1[cf]);
            atomAdd(&gsq[slot + cf * 16 + c0], s2[cf]);
        }
    }
}

__global__ void bn_finalize(const float* __restrict__ gsums, const float* __restrict__ gsq,
                            const float* __restrict__ gamma,
                            const float* __restrict__ beta,
                            float* __restrict__ scale, float* __restrict__ shift) {
    int d = threadIdx.x;  // 128
    float s1 = 0.f, s2 = 0.f;
    for (int c = 0; c < 32; ++c) { s1 += gsums[c * DD + d]; s2 += gsq[c * DD + d]; }
    float mean = s1 / (float)NN;
    float var  = s2 / (float)NN - mean * mean;
    float sc = gamma[d] * rsqrtf(var + BN_EPS);
    scale[d] = sc;
    shift[d] = beta[d] - mean * sc;
}

// out = feat_bf + relu(t*scale + shift)   (both bf16 inputs, f32 out)
__global__ void epilogue(const ushort_t* __restrict__ t, const ushort_t* __restrict__ featb,
                         const float* __restrict__ scale, const float* __restrict__ shift,
                         float* __restrict__ out) {
    int i = blockIdx.x * 256 + threadIdx.x;
    if (i >= NN * DD / 4) return;
    int d0 = (i << 2) & 127;
    ushort4 tv = reinterpret_cast<const ushort4*>(t)[i];
    ushort4 fv = reinterpret_cast<const ushort4*>(featb)[i];
    float4 o;
    o.x = b2f(fv.x) + fmaxf(b2f(tv.x) * scale[d0 + 0] + shift[d0 + 0], 0.f);
    o.y = b2f(fv.y) + fmaxf(b2f(tv.y) * scale[d0 + 1] + shift[d0 + 1], 0.f);
    o.z = b2f(fv.z) + fmaxf(b2f(tv.z) * scale[d0 + 2] + shift[d0 + 2], 0.f);
    o.w = b2f(fv.w) + fmaxf(b2f(tv.w) * scale[d0 + 3] + shift[d0 + 3], 0.f);
    reinterpret_cast<float4*>(out)[i] = o;
}

extern "C" void kernel_launch(void* const* d_in, const int* in_sizes, int n_in,
                              void* d_out, int out_size, void* d_ws, size_t ws_size,
                              hipStream_t stream) {
    const float* feat  = (const float*)d_in[0];
    const float* snorm = (const float*)d_in[1];
    const float* W1    = (const float*)d_in[2];
    const float* W2    = (const float*)d_in[3];
    const float* W3    = (const float*)d_in[4];
    const float* bias  = (const float*)d_in[5];
    const float* gamma = (const float*)d_in[6];
    const float* beta  = (const float*)d_in[7];
    const int* esrc = (const int*)d_in[8];
    const int* edst = (const int*)d_in[9];
    float* out = (float*)d_out;

    char* ws = (char*)d_ws;
    ushort_t* t_bf    = (ushort_t*)(ws);                 // 12,800,000 (gemm output)
    int*      epos    = (int*)     (ws);                 //  3,200,000 ALIAS of t_bf
                                                         //  (epos dead before gemm_bn runs)
    ushort_t* feat_bf = (ushort_t*)(ws + 12800000);      // 12,800,000
    ushort_t* ax_bf   = (ushort_t*)(ws + 25600000);      // 12,800,000
    ushort_t* ax2_bf  = (ushort_t*)(ws + 38400000);      // 12,800,000
    int2*     csr     = (int2*)    (ws + 51200000);      //  6,400,000 (src, norm bits)
    float*    norm    = (float*)   (ws + 57600000);      //    200,000
    int*      cnt     = (int*)     (ws + 57800000);      //    200,000 (-> deg)
    float*    gsums   = (float*)   (ws + 58000000);      //     16,384
    float*    gsq     = (float*)   (ws + 58016384);      //     16,384
    int*      off     = (int*)     (ws + 58032768);      //    200,064
    int*      part    = (int*)     (ws + 58232832);      //        512
    float*    scale   = (float*)   (ws + 58233856);      //        512
    float*    shift   = (float*)   (ws + 58234368);      //        512
    ushort_t* wcT     = (ushort_t*)(ws + 58234880);      //     98,304 (end 58,333,184)

    hipMemsetAsync(ws + 57800000, 0, 232768, stream);    // cnt, gsums, gsq

    epos_kernel<<<3125, 256, 0, stream>>>(edst, cnt, epos);
    scan_part  <<<SCAN_G, 512, 0, stream>>>(cnt, part, norm);
    scan_final <<<SCAN_G, 512, 0, stream>>>(cnt, part, off);
    fill_kernel<<<3125, 256, 0, stream>>>(esrc, edst, epos, off, norm, csr);

    prep_kernel<<<6442, 256, 0, stream>>>(feat, feat_bf, W1, W2, W3, wcT);

    gather_bf<<<12500, 256, 0, stream>>>(feat_bf, norm, off, csr, ax_bf);
    gather_bf<<<12500, 256, 0, stream>>>(ax_bf,   norm, off, csr, ax2_bf);

    gemm_bn<<<391, 256, 0, stream>>>(feat_bf, ax_bf, ax2_bf, wcT, bias, snorm,
                                     t_bf, gsums, gsq);
    bn_finalize<<<1, 128, 0, stream>>>(gsums, gsq, gamma, beta, scale, shift);
    epilogue   <<<6250, 256, 0, stream>>>(t_bf, feat_bf, scale, shift, out);
}

// Round 13
// 166.826 us; speedup vs baseline: 1.8141x; 1.0526x over previous
//
#include <hip/hip_runtime.h>
#include <hip/hip_bf16.h>

#define NN 50000
#define NE 800000
#define DD 128
#define BN_EPS 1e-5f
#define SCAN_G 98    // 98*512 = 50176 >= NN

typedef unsigned short ushort_t;
typedef unsigned int uint_t;
typedef __attribute__((ext_vector_type(8))) short short8v;   // 8 x bf16 (4 VGPR)
typedef __attribute__((ext_vector_type(4))) float f32x4;

__device__ __forceinline__ float b2f(ushort_t u) {
    union { uint_t i; float f; } v; v.i = ((uint_t)u) << 16; return v.f;
}
__device__ __forceinline__ ushort_t f2b(float f) {
    uint_t u = __float_as_uint(f);
    u += 0x7FFFu + ((u >> 16) & 1u);   // RNE
    return (ushort_t)(u >> 16);
}
__device__ __forceinline__ void atomAdd(float* p, float v) { unsafeAtomicAdd(p, v); }

// ---------- graph prep + feat->bf16 (fused) ----------
// epos[e] = position of edge e within its dst bucket; cnt ends as deg.
// Each thread also converts 8 feat floats to bf16 (hides atomic latency).
__global__ void epos_prep(const int* __restrict__ dst, int* __restrict__ cnt,
                          int* __restrict__ epos,
                          const float* __restrict__ feat, ushort_t* __restrict__ feat_bf) {
    int e = blockIdx.x * 256 + threadIdx.x;      // 3125*256 = 800000 exactly
    {
        const float4* fp = reinterpret_cast<const float4*>(feat);
        ushort4* op = reinterpret_cast<ushort4*>(feat_bf);
        int i = e << 1;                          // 2 float4 per thread, 1.6M total
        float4 v0 = fp[i], v1 = fp[i + 1];
        ushort4 o0 = { f2b(v0.x), f2b(v0.y), f2b(v0.z), f2b(v0.w) };
        ushort4 o1 = { f2b(v1.x), f2b(v1.y), f2b(v1.z), f2b(v1.w) };
        op[i] = o0; op[i + 1] = o1;
    }
    epos[e] = atomicAdd(&cnt[dst[e]], 1);
}

// pass 1: per-block (512 elems) sums; also emits norm = rsqrt(max(deg,1))
__global__ __launch_bounds__(512) void scan_part(const int* __restrict__ deg,
                                                 int* __restrict__ part,
                                                 float* __restrict__ norm) {
    int i = blockIdx.x * 512 + threadIdx.x;
    int v = (i < NN) ? deg[i] : 0;
    if (i < NN) norm[i] = rsqrtf((float)max(v, 1));
    int s = v;
    #pragma unroll
    for (int k = 1; k < 64; k <<= 1) s += __shfl_xor(s, k);
    __shared__ int wsum[8];
    if ((threadIdx.x & 63) == 0) wsum[threadIdx.x >> 6] = s;
    __syncthreads();
    if (threadIdx.x == 0) {
        int t = 0;
        #pragma unroll
        for (int k = 0; k < 8; ++k) t += wsum[k];
        part[blockIdx.x] = t;
    }
}

// pass 2 (blocks < SCAN_G): block-local exclusive scan + in-block base.
// blocks >= SCAN_G: build WcT (128x384 bf16): k<128: W1-W3; k<256: -W2; else 2*W3.
__global__ __launch_bounds__(512) void scan_final(const int* __restrict__ deg,
                                                  const int* __restrict__ part,
                                                  int* __restrict__ off,
                                                  const float* __restrict__ W1,
                                                  const float* __restrict__ W2,
                                                  const float* __restrict__ W3,
                                                  ushort_t* __restrict__ wcT) {
    if (blockIdx.x >= SCAN_G) {
        int i = (blockIdx.x - SCAN_G) * 512 + threadIdx.x;   // 96*512 = 49152 = 128*384
        int d = i / 384, k = i % 384;
        float v;
        if (k < 128)      v = W1[k * DD + d] - W3[k * DD + d];
        else if (k < 256) v = -W2[(k - 128) * DD + d];
        else              v = 2.0f * W3[(k - 256) * DD + d];
        wcT[i] = f2b(v);
        return;
    }
    __shared__ int wsum[8];
    __shared__ int sbase;
    int t = threadIdx.x;
    int lane = t & 63, wv = t >> 6;

    int p = (t < blockIdx.x && t < SCAN_G) ? part[t] : 0;
    #pragma unroll
    for (int s = 1; s < 64; s <<= 1) p += __shfl_xor(p, s);
    if (lane == 0) wsum[wv] = p;
    __syncthreads();
    if (t == 0) {
        int b = 0;
        #pragma unroll
        for (int k = 0; k < 8; ++k) b += wsum[k];
        sbase = b;
    }
    __syncthreads();

    int i = blockIdx.x * 512 + t;
    int v = (i < NN) ? deg[i] : 0;
    int incl = v;
    #pragma unroll
    for (int s = 1; s < 64; s <<= 1) {
        int u = __shfl_up(incl, s);
        if (lane >= s) incl += u;
    }
    __syncthreads();
    if (lane == 63) wsum[wv] = incl;
    __syncthreads();
    int woff = 0;
    for (int k = 0; k < wv; ++k) woff += wsum[k];
    int excl = sbase + woff + incl - v;
    if (i < NN) off[i] = excl;
    if (blockIdx.x == 0 && t == 0) off[NN] = NE;
}

// csr[off[dst]+epos] = (src, bits(norm[src])) — atomic-free scatter
__global__ void fill_kernel(const int* __restrict__ src, const int* __restrict__ dst,
                            const int* __restrict__ epos, const int* __restrict__ off,
                            const float* __restrict__ norm, int2* __restrict__ csr) {
    int e = blockIdx.x * 256 + threadIdx.x;
    if (e >= NE) return;
    int s = src[e];
    int p = off[dst[e]] + epos[e];
    csr[p] = make_int2(s, __float_as_int(norm[s]));
}

// ---------- message passing (bf16 in, bf16 out) ----------
// QUARTER-WAVE (16 lanes) per NODE; lane covers 8 cols (uint4 = 16B).
// 4-deep unroll => 4 independent row loads per group, 16 per wave, sustained.
// Lane's accumulator IS its 8 output cols — no cross-lane reduction.
__global__ __launch_bounds__(256) void gather_bf(const ushort_t* __restrict__ x,
                                                 const float* __restrict__ norm,
                                                 const int* __restrict__ off,
                                                 const int2* __restrict__ csr,
                                                 ushort_t* __restrict__ out) {
    int g = (blockIdx.x << 4) | (threadIdx.x >> 4);   // node id; 3125*16 = 50000
    int l4 = threadIdx.x & 15;
    int jb = off[g], je = off[g + 1];
    const uint4* xp = reinterpret_cast<const uint4*>(x);   // row = 16 x uint4
    float a0 = 0.f, a1 = 0.f, a2 = 0.f, a3 = 0.f;
    float a4 = 0.f, a5 = 0.f, a6 = 0.f, a7 = 0.f;

#define ACC(cc, vv)                                                  \
    {                                                                \
        float n_ = __int_as_float(cc.y);                             \
        a0 = fmaf(n_, b2f((ushort_t)(vv.x)), a0);                    \
        a1 = fmaf(n_, b2f((ushort_t)(vv.x >> 16)), a1);              \
        a2 = fmaf(n_, b2f((ushort_t)(vv.y)), a2);                    \
        a3 = fmaf(n_, b2f((ushort_t)(vv.y >> 16)), a3);              \
        a4 = fmaf(n_, b2f((ushort_t)(vv.z)), a4);                    \
        a5 = fmaf(n_, b2f((ushort_t)(vv.z >> 16)), a5);              \
        a6 = fmaf(n_, b2f((ushort_t)(vv.w)), a6);                    \
        a7 = fmaf(n_, b2f((ushort_t)(vv.w >> 16)), a7);              \
    }

    int j = jb;
    for (; j + 4 <= je; j += 4) {
        int2 c0 = csr[j + 0];
        int2 c1 = csr[j + 1];
        int2 c2 = csr[j + 2];
        int2 c3 = csr[j + 3];
        uint4 v0 = xp[(size_t)c0.x * 16 + l4];
        uint4 v1 = xp[(size_t)c1.x * 16 + l4];
        uint4 v2 = xp[(size_t)c2.x * 16 + l4];
        uint4 v3 = xp[(size_t)c3.x * 16 + l4];
        ACC(c0, v0); ACC(c1, v1); ACC(c2, v2); ACC(c3, v3);
    }
    for (; j < je; ++j) {
        int2 c = csr[j];
        uint4 v = xp[(size_t)c.x * 16 + l4];
        ACC(c, v);
    }
#undef ACC

    float nd = norm[g];
    uint4 o;
    o.x = (uint_t)f2b(nd * a0) | ((uint_t)f2b(nd * a1) << 16);
    o.y = (uint_t)f2b(nd * a2) | ((uint_t)f2b(nd * a3) << 16);
    o.z = (uint_t)f2b(nd * a4) | ((uint_t)f2b(nd * a5) << 16);
    o.w = (uint_t)f2b(nd * a6) | ((uint_t)f2b(nd * a7) << 16);
    reinterpret_cast<uint4*>(out)[(size_t)g * 16 + l4] = o;
}

// ---------- MFMA GEMM + BN partials ----------
// 128-row blocks, 4 waves; wave owns 32 rows x 128 cols (2 row-groups).
__global__ __launch_bounds__(256) void gemm_bn(
    const ushort_t* __restrict__ feat_bf, const ushort_t* __restrict__ ax_bf,
    const ushort_t* __restrict__ ax2_bf, const ushort_t* __restrict__ wcT,
    const float* __restrict__ bias, const float* __restrict__ snorm,
    ushort_t* __restrict__ t_out, float* __restrict__ gsums, float* __restrict__ gsq)
{
    __shared__ ushort_t As[128 * 128];   // 32 KB, XOR-swizzled
    __shared__ ushort_t Bs[128 * 128];   // 32 KB, XOR-swizzled
    int tid = threadIdx.x;
    int w = tid >> 6, lane = tid & 63;
    int row0 = blockIdx.x * 128;

    f32x4 acc[2][8] = {};

    #pragma unroll
    for (int kt = 0; kt < 3; ++kt) {
        const ushort_t* S = (kt == 0) ? feat_bf : (kt == 1) ? ax_bf : ax2_bf;
        __syncthreads();
        {
            int r = tid >> 1, hh = tid & 1;
            int grow = min(row0 + r, NN - 1);
            const char* gsrc = (const char*)(S + grow * DD);
            char* dbase = (char*)As + r * 256;
            int sw = (r & 7) << 4;
            #pragma unroll
            for (int c = 0; c < 8; ++c) {
                int cb = hh * 128 + c * 16;
                *(short8v*)(dbase + (cb ^ sw)) = *(const short8v*)(gsrc + cb);
            }
        }
        {
            int cidx = tid >> 1, hh = tid & 1;
            const char* gsrc = (const char*)(wcT + cidx * 384 + kt * 128);
            char* dbase = (char*)Bs + cidx * 256;
            int sw = (cidx & 7) << 4;
            #pragma unroll
            for (int c = 0; c < 8; ++c) {
                int cb = hh * 128 + c * 16;
                *(short8v*)(dbase + (cb ^ sw)) = *(const short8v*)(gsrc + cb);
            }
        }
        __syncthreads();
        int l15 = lane & 15;
        int r0a = w * 32 + l15;
        int r1a = r0a + 16;
        #pragma unroll
        for (int ks = 0; ks < 4; ++ks) {
            int kb = ks * 64 + ((lane >> 4) << 4);
            short8v a0 = *(const short8v*)((const char*)As + r0a * 256 + (kb ^ ((r0a & 7) << 4)));
            short8v a1 = *(const short8v*)((const char*)As + r1a * 256 + (kb ^ ((r1a & 7) << 4)));
            #pragma unroll
            for (int cf = 0; cf < 8; ++cf) {
                int col = cf * 16 + l15;
                short8v b = *(const short8v*)((const char*)Bs + col * 256 + (kb ^ ((col & 7) << 4)));
                acc[0][cf] = __builtin_amdgcn_mfma_f32_16x16x32_bf16(a0, b, acc[0][cf], 0, 0, 0);
                acc[1][cf] = __builtin_amdgcn_mfma_f32_16x16x32_bf16(a1, b, acc[1][cf], 0, 0, 0);
            }
        }
    }

    int q = lane >> 4, c0 = lane & 15;
    float s1[8], s2[8];
    #pragma unroll
    for (int cf = 0; cf < 8; ++cf) { s1[cf] = 0.f; s2[cf] = 0.f; }

    #pragma unroll
    for (int g = 0; g < 2; ++g) {
        int rbase = row0 + w * 32 + g * 16 + q * 4;
        float sn[4];
        #pragma unroll
        for (int i = 0; i < 4; ++i) sn[i] = (rbase + i < NN) ? snorm[rbase + i] : 0.f;
        #pragma unroll
        for (int cf = 0; cf < 8; ++cf) {
            int col = cf * 16 + c0;
            float bc = bias[col];
            #pragma unroll
            for (int i = 0; i < 4; ++i) {
                int row = rbase + i;
                if (row < NN) {
                    float t = (acc[g][cf][i] + bc) * sn[i];
                    t_out[row * DD + col] = f2b(t);
                    s1[cf] += t; s2[cf] += t * t;
                }
            }
        }
    }
    #pragma unroll
    for (int cf = 0; cf < 8; ++cf) {
        s1[cf] += __shfl_xor(s1[cf], 16); s1[cf] += __shfl_xor(s1[cf], 32);
        s2[cf] += __shfl_xor(s2[cf], 16); s2[cf] += __shfl_xor(s2[cf], 32);
    }
    if (q == 0) {
        int slot = (blockIdx.x & 31) * DD;
        #pragma unroll
        for (int cf = 0; cf < 8; ++cf) {
            atomAdd(&gsums[slot + cf * 16 + c0], s1[cf]);
            atomAdd(&gsq[slot + cf * 16 + c0], s2[cf]);
        }
    }
}

__global__ void bn_finalize(const float* __restrict__ gsums, const float* __restrict__ gsq,
                            const float* __restrict__ gamma,
                            const float* __restrict__ beta,
                            float* __restrict__ scale, float* __restrict__ shift) {
    int d = threadIdx.x;  // 128
    float s1 = 0.f, s2 = 0.f;
    for (int c = 0; c < 32; ++c) { s1 += gsums[c * DD + d]; s2 += gsq[c * DD + d]; }
    float mean = s1 / (float)NN;
    float var  = s2 / (float)NN - mean * mean;
    float sc = gamma[d] * rsqrtf(var + BN_EPS);
    scale[d] = sc;
    shift[d] = beta[d] - mean * sc;
}

// out = feat_bf + relu(t*scale + shift)   (both bf16 inputs, f32 out)
__global__ void epilogue(const ushort_t* __restrict__ t, const ushort_t* __restrict__ featb,
                         const float* __restrict__ scale, const float* __restrict__ shift,
                         float* __restrict__ out) {
    int i = blockIdx.x * 256 + threadIdx.x;
    if (i >= NN * DD / 4) return;
    int d0 = (i << 2) & 127;
    ushort4 tv = reinterpret_cast<const ushort4*>(t)[i];
    ushort4 fv = reinterpret_cast<const ushort4*>(featb)[i];
    float4 o;
    o.x = b2f(fv.x) + fmaxf(b2f(tv.x) * scale[d0 + 0] + shift[d0 + 0], 0.f);
    o.y = b2f(fv.y) + fmaxf(b2f(tv.y) * scale[d0 + 1] + shift[d0 + 1], 0.f);
    o.z = b2f(fv.z) + fmaxf(b2f(tv.z) * scale[d0 + 2] + shift[d0 + 2], 0.f);
    o.w = b2f(fv.w) + fmaxf(b2f(tv.w) * scale[d0 + 3] + shift[d0 + 3], 0.f);
    reinterpret_cast<float4*>(out)[i] = o;
}

extern "C" void kernel_launch(void* const* d_in, const int* in_sizes, int n_in,
                              void* d_out, int out_size, void* d_ws, size_t ws_size,
                              hipStream_t stream) {
    const float* feat  = (const float*)d_in[0];
    const float* snorm = (const float*)d_in[1];
    const float* W1    = (const float*)d_in[2];
    const float* W2    = (const float*)d_in[3];
    const float* W3    = (const float*)d_in[4];
    const float* bias  = (const float*)d_in[5];
    const float* gamma = (const float*)d_in[6];
    const float* beta  = (const float*)d_in[7];
    const int* esrc = (const int*)d_in[8];
    const int* edst = (const int*)d_in[9];
    float* out = (float*)d_out;

    char* ws = (char*)d_ws;
    ushort_t* t_bf    = (ushort_t*)(ws);                 // 12,800,000 (gemm output)
    int*      epos    = (int*)     (ws);                 //  3,200,000 ALIAS of t_bf
                                                         //  (epos dead before gemm_bn runs)
    ushort_t* feat_bf = (ushort_t*)(ws + 12800000);      // 12,800,000
    ushort_t* ax_bf   = (ushort_t*)(ws + 25600000);      // 12,800,000
    ushort_t* ax2_bf  = (ushort_t*)(ws + 38400000);      // 12,800,000
    int2*     csr     = (int2*)    (ws + 51200000);      //  6,400,000 (src, norm bits)
    float*    norm    = (float*)   (ws + 57600000);      //    200,000
    int*      cnt     = (int*)     (ws + 57800000);      //    200,000 (-> deg)
    float*    gsums   = (float*)   (ws + 58000000);      //     16,384
    float*    gsq     = (float*)   (ws + 58016384);      //     16,384
    int*      off     = (int*)     (ws + 58032768);      //    200,064
    int*      part    = (int*)     (ws + 58232832);      //        512
    float*    scale   = (float*)   (ws + 58233856);      //        512
    float*    shift   = (float*)   (ws + 58234368);      //        512
    ushort_t* wcT     = (ushort_t*)(ws + 58234880);      //     98,304 (end 58,333,184)

    hipMemsetAsync(ws + 57800000, 0, 232768, stream);    // cnt, gsums, gsq

    epos_prep  <<<3125, 256, 0, stream>>>(edst, cnt, epos, feat, feat_bf);
    scan_part  <<<SCAN_G, 512, 0, stream>>>(cnt, part, norm);
    scan_final <<<SCAN_G + 96, 512, 0, stream>>>(cnt, part, off, W1, W2, W3, wcT);
    fill_kernel<<<3125, 256, 0, stream>>>(esrc, edst, epos, off, norm, csr);

    gather_bf<<<3125, 256, 0, stream>>>(feat_bf, norm, off, csr, ax_bf);
    gather_bf<<<3125, 256, 0, stream>>>(ax_bf,   norm, off, csr, ax2_bf);

    gemm_bn<<<391, 256, 0, stream>>>(feat_bf, ax_bf, ax2_bf, wcT, bias, snorm,
                                     t_bf, gsums, gsq);
    bn_finalize<<<1, 128, 0, stream>>>(gsums, gsq, gamma, beta, scale, shift);
    epilogue   <<<6250, 256, 0, stream>>>(t_bf, feat_bf, scale, shift, out);
}

// Round 14
// 166.300 us; speedup vs baseline: 1.8198x; 1.0032x over previous
//
#include <hip/hip_runtime.h>
#include <hip/hip_bf16.h>

#define NN 50000
#define NE 800000
#define DD 128
#define BN_EPS 1e-5f
#define SCAN_G 98    // 98*512 = 50176 >= NN

typedef unsigned short ushort_t;
typedef unsigned int uint_t;
typedef __attribute__((ext_vector_type(8))) short short8v;   // 8 x bf16 (4 VGPR)
typedef __attribute__((ext_vector_type(4))) float f32x4;

__device__ __forceinline__ float b2f(ushort_t u) {
    union { uint_t i; float f; } v; v.i = ((uint_t)u) << 16; return v.f;
}
__device__ __forceinline__ ushort_t f2b(float f) {
    uint_t u = __float_as_uint(f);
    u += 0x7FFFu + ((u >> 16) & 1u);   // RNE
    return (ushort_t)(u >> 16);
}
__device__ __forceinline__ void atomAdd(float* p, float v) { unsafeAtomicAdd(p, v); }

// ---------- graph prep + feat->bf16 (fused) ----------
// cnt_pad: ONE counter per 64B line (dst<<4) — kills per-line RMW serialization.
__global__ void epos_prep(const int* __restrict__ dst, int* __restrict__ cnt_pad,
                          int* __restrict__ epos,
                          const float* __restrict__ feat, ushort_t* __restrict__ feat_bf) {
    int e = blockIdx.x * 256 + threadIdx.x;      // 3125*256 = 800000 exactly
    {
        const float4* fp = reinterpret_cast<const float4*>(feat);
        ushort4* op = reinterpret_cast<ushort4*>(feat_bf);
        int i = e << 1;                          // 2 float4 per thread, 1.6M total
        float4 v0 = fp[i], v1 = fp[i + 1];
        ushort4 o0 = { f2b(v0.x), f2b(v0.y), f2b(v0.z), f2b(v0.w) };
        ushort4 o1 = { f2b(v1.x), f2b(v1.y), f2b(v1.z), f2b(v1.w) };
        op[i] = o0; op[i + 1] = o1;
    }
    epos[e] = atomicAdd(&cnt_pad[dst[e] << 4], 1);
}

// pass 1: per-block (512 elems) sums; also emits norm = rsqrt(max(deg,1))
__global__ __launch_bounds__(512) void scan_part(const int* __restrict__ cnt_pad,
                                                 int* __restrict__ part,
                                                 float* __restrict__ norm) {
    int i = blockIdx.x * 512 + threadIdx.x;
    int v = (i < NN) ? cnt_pad[i << 4] : 0;
    if (i < NN) norm[i] = rsqrtf((float)max(v, 1));
    int s = v;
    #pragma unroll
    for (int k = 1; k < 64; k <<= 1) s += __shfl_xor(s, k);
    __shared__ int wsum[8];
    if ((threadIdx.x & 63) == 0) wsum[threadIdx.x >> 6] = s;
    __syncthreads();
    if (threadIdx.x == 0) {
        int t = 0;
        #pragma unroll
        for (int k = 0; k < 8; ++k) t += wsum[k];
        part[blockIdx.x] = t;
    }
}

// pass 2 (blocks < SCAN_G): block-local exclusive scan + in-block base.
// blocks >= SCAN_G: build WcT (128x384 bf16): k<128: W1-W3; k<256: -W2; else 2*W3.
__global__ __launch_bounds__(512) void scan_final(const int* __restrict__ cnt_pad,
                                                  const int* __restrict__ part,
                                                  int* __restrict__ off,
                                                  const float* __restrict__ W1,
                                                  const float* __restrict__ W2,
                                                  const float* __restrict__ W3,
                                                  ushort_t* __restrict__ wcT) {
    if (blockIdx.x >= SCAN_G) {
        int i = (blockIdx.x - SCAN_G) * 512 + threadIdx.x;   // 96*512 = 49152 = 128*384
        int d = i / 384, k = i % 384;
        float v;
        if (k < 128)      v = W1[k * DD + d] - W3[k * DD + d];
        else if (k < 256) v = -W2[(k - 128) * DD + d];
        else              v = 2.0f * W3[(k - 256) * DD + d];
        wcT[i] = f2b(v);
        return;
    }
    __shared__ int wsum[8];
    __shared__ int sbase;
    int t = threadIdx.x;
    int lane = t & 63, wv = t >> 6;

    int p = (t < blockIdx.x && t < SCAN_G) ? part[t] : 0;
    #pragma unroll
    for (int s = 1; s < 64; s <<= 1) p += __shfl_xor(p, s);
    if (lane == 0) wsum[wv] = p;
    __syncthreads();
    if (t == 0) {
        int b = 0;
        #pragma unroll
        for (int k = 0; k < 8; ++k) b += wsum[k];
        sbase = b;
    }
    __syncthreads();

    int i = blockIdx.x * 512 + t;
    int v = (i < NN) ? cnt_pad[i << 4] : 0;
    int incl = v;
    #pragma unroll
    for (int s = 1; s < 64; s <<= 1) {
        int u = __shfl_up(incl, s);
        if (lane >= s) incl += u;
    }
    __syncthreads();
    if (lane == 63) wsum[wv] = incl;
    __syncthreads();
    int woff = 0;
    for (int k = 0; k < wv; ++k) woff += wsum[k];
    int excl = sbase + woff + incl - v;
    if (i < NN) off[i] = excl;
    if (blockIdx.x == 0 && t == 0) off[NN] = NE;
}

// csr[off[dst]+epos] = (src, bits(norm[src])) — atomic-free scatter
__global__ void fill_kernel(const int* __restrict__ src, const int* __restrict__ dst,
                            const int* __restrict__ epos, const int* __restrict__ off,
                            const float* __restrict__ norm, int2* __restrict__ csr) {
    int e = blockIdx.x * 256 + threadIdx.x;
    if (e >= NE) return;
    int s = src[e];
    int p = off[dst[e]] + epos[e];
    csr[p] = make_int2(s, __float_as_int(norm[s]));
}

// ---------- message passing (bf16 in, bf16 out) ----------
// QUARTER-WAVE (16 lanes) per NODE; lane covers 8 cols (uint4 = 16B).
// 4-deep unroll => 4 independent row loads per group, 16 per wave, sustained.
__global__ __launch_bounds__(256) void gather_bf(const ushort_t* __restrict__ x,
                                                 const float* __restrict__ norm,
                                                 const int* __restrict__ off,
                                                 const int2* __restrict__ csr,
                                                 ushort_t* __restrict__ out) {
    int g = (blockIdx.x << 4) | (threadIdx.x >> 4);   // node id; 3125*16 = 50000
    int l4 = threadIdx.x & 15;
    int jb = off[g], je = off[g + 1];
    const uint4* xp = reinterpret_cast<const uint4*>(x);   // row = 16 x uint4
    float a0 = 0.f, a1 = 0.f, a2 = 0.f, a3 = 0.f;
    float a4 = 0.f, a5 = 0.f, a6 = 0.f, a7 = 0.f;

#define ACC(cc, vv)                                                  \
    {                                                                \
        float n_ = __int_as_float(cc.y);                             \
        a0 = fmaf(n_, b2f((ushort_t)(vv.x)), a0);                    \
        a1 = fmaf(n_, b2f((ushort_t)(vv.x >> 16)), a1);              \
        a2 = fmaf(n_, b2f((ushort_t)(vv.y)), a2);                    \
        a3 = fmaf(n_, b2f((ushort_t)(vv.y >> 16)), a3);              \
        a4 = fmaf(n_, b2f((ushort_t)(vv.z)), a4);                    \
        a5 = fmaf(n_, b2f((ushort_t)(vv.z >> 16)), a5);              \
        a6 = fmaf(n_, b2f((ushort_t)(vv.w)), a6);                    \
        a7 = fmaf(n_, b2f((ushort_t)(vv.w >> 16)), a7);              \
    }

    int j = jb;
    for (; j + 4 <= je; j += 4) {
        int2 c0 = csr[j + 0];
        int2 c1 = csr[j + 1];
        int2 c2 = csr[j + 2];
        int2 c3 = csr[j + 3];
        uint4 v0 = xp[(size_t)c0.x * 16 + l4];
        uint4 v1 = xp[(size_t)c1.x * 16 + l4];
        uint4 v2 = xp[(size_t)c2.x * 16 + l4];
        uint4 v3 = xp[(size_t)c3.x * 16 + l4];
        ACC(c0, v0); ACC(c1, v1); ACC(c2, v2); ACC(c3, v3);
    }
    for (; j < je; ++j) {
        int2 c = csr[j];
        uint4 v = xp[(size_t)c.x * 16 + l4];
        ACC(c, v);
    }
#undef ACC

    float nd = norm[g];
    uint4 o;
    o.x = (uint_t)f2b(nd * a0) | ((uint_t)f2b(nd * a1) << 16);
    o.y = (uint_t)f2b(nd * a2) | ((uint_t)f2b(nd * a3) << 16);
    o.z = (uint_t)f2b(nd * a4) | ((uint_t)f2b(nd * a5) << 16);
    o.w = (uint_t)f2b(nd * a6) | ((uint_t)f2b(nd * a7) << 16);
    reinterpret_cast<uint4*>(out)[(size_t)g * 16 + l4] = o;
}

// ---------- MFMA GEMM + BN partials ----------
// 128-row blocks, 4 waves; wave owns 32 rows x 128 cols (2 row-groups).
__global__ __launch_bounds__(256) void gemm_bn(
    const ushort_t* __restrict__ feat_bf, const ushort_t* __restrict__ ax_bf,
    const ushort_t* __restrict__ ax2_bf, const ushort_t* __restrict__ wcT,
    const float* __restrict__ bias, const float* __restrict__ snorm,
    ushort_t* __restrict__ t_out, float* __restrict__ gsums, float* __restrict__ gsq)
{
    __shared__ ushort_t As[128 * 128];   // 32 KB, XOR-swizzled
    __shared__ ushort_t Bs[128 * 128];   // 32 KB, XOR-swizzled
    int tid = threadIdx.x;
    int w = tid >> 6, lane = tid & 63;
    int row0 = blockIdx.x * 128;

    f32x4 acc[2][8] = {};

    #pragma unroll
    for (int kt = 0; kt < 3; ++kt) {
        const ushort_t* S = (kt == 0) ? feat_bf : (kt == 1) ? ax_bf : ax2_bf;
        __syncthreads();
        {
            int r = tid >> 1, hh = tid & 1;
            int grow = min(row0 + r, NN - 1);
            const char* gsrc = (const char*)(S + grow * DD);
            char* dbase = (char*)As + r * 256;
            int sw = (r & 7) << 4;
            #pragma unroll
            for (int c = 0; c < 8; ++c) {
                int cb = hh * 128 + c * 16;
                *(short8v*)(dbase + (cb ^ sw)) = *(const short8v*)(gsrc + cb);
            }
        }
        {
            int cidx = tid >> 1, hh = tid & 1;
            const char* gsrc = (const char*)(wcT + cidx * 384 + kt * 128);
            char* dbase = (char*)Bs + cidx * 256;
            int sw = (cidx & 7) << 4;
            #pragma unroll
            for (int c = 0; c < 8; ++c) {
                int cb = hh * 128 + c * 16;
                *(short8v*)(dbase + (cb ^ sw)) = *(const short8v*)(gsrc + cb);
            }
        }
        __syncthreads();
        int l15 = lane & 15;
        int r0a = w * 32 + l15;
        int r1a = r0a + 16;
        #pragma unroll
        for (int ks = 0; ks < 4; ++ks) {
            int kb = ks * 64 + ((lane >> 4) << 4);
            short8v a0 = *(const short8v*)((const char*)As + r0a * 256 + (kb ^ ((r0a & 7) << 4)));
            short8v a1 = *(const short8v*)((const char*)As + r1a * 256 + (kb ^ ((r1a & 7) << 4)));
            #pragma unroll
            for (int cf = 0; cf < 8; ++cf) {
                int col = cf * 16 + l15;
                short8v b = *(const short8v*)((const char*)Bs + col * 256 + (kb ^ ((col & 7) << 4)));
                acc[0][cf] = __builtin_amdgcn_mfma_f32_16x16x32_bf16(a0, b, acc[0][cf], 0, 0, 0);
                acc[1][cf] = __builtin_amdgcn_mfma_f32_16x16x32_bf16(a1, b, acc[1][cf], 0, 0, 0);
            }
        }
    }

    int q = lane >> 4, c0 = lane & 15;
    float s1[8], s2[8];
    #pragma unroll
    for (int cf = 0; cf < 8; ++cf) { s1[cf] = 0.f; s2[cf] = 0.f; }

    #pragma unroll
    for (int g = 0; g < 2; ++g) {
        int rbase = row0 + w * 32 + g * 16 + q * 4;
        float sn[4];
        #pragma unroll
        for (int i = 0; i < 4; ++i) sn[i] = (rbase + i < NN) ? snorm[rbase + i] : 0.f;
        #pragma unroll
        for (int cf = 0; cf < 8; ++cf) {
            int col = cf * 16 + c0;
            float bc = bias[col];
            #pragma unroll
            for (int i = 0; i < 4; ++i) {
                int row = rbase + i;
                if (row < NN) {
                    float t = (acc[g][cf][i] + bc) * sn[i];
                    t_out[row * DD + col] = f2b(t);
                    s1[cf] += t; s2[cf] += t * t;
                }
            }
        }
    }
    #pragma unroll
    for (int cf = 0; cf < 8; ++cf) {
        s1[cf] += __shfl_xor(s1[cf], 16); s1[cf] += __shfl_xor(s1[cf], 32);
        s2[cf] += __shfl_xor(s2[cf], 16); s2[cf] += __shfl_xor(s2[cf], 32);
    }
    if (q == 0) {
        int slot = (blockIdx.x & 31) * DD;
        #pragma unroll
        for (int cf = 0; cf < 8; ++cf) {
            atomAdd(&gsums[slot + cf * 16 + c0], s1[cf]);
            atomAdd(&gsq[slot + cf * 16 + c0], s2[cf]);
        }
    }
}

__global__ void bn_finalize(const float* __restrict__ gsums, const float* __restrict__ gsq,
                            const float* __restrict__ gamma,
                            const float* __restrict__ beta,
                            float* __restrict__ scale, float* __restrict__ shift) {
    int d = threadIdx.x;  // 128
    float s1 = 0.f, s2 = 0.f;
    for (int c = 0; c < 32; ++c) { s1 += gsums[c * DD + d]; s2 += gsq[c * DD + d]; }
    float mean = s1 / (float)NN;
    float var  = s2 / (float)NN - mean * mean;
    float sc = gamma[d] * rsqrtf(var + BN_EPS);
    scale[d] = sc;
    shift[d] = beta[d] - mean * sc;
}

// out = feat_bf + relu(t*scale + shift)   (both bf16 inputs, f32 out)
__global__ void epilogue(const ushort_t* __restrict__ t, const ushort_t* __restrict__ featb,
                         const float* __restrict__ scale, const float* __restrict__ shift,
                         float* __restrict__ out) {
    int i = blockIdx.x * 256 + threadIdx.x;
    if (i >= NN * DD / 4) return;
    int d0 = (i << 2) & 127;
    ushort4 tv = reinterpret_cast<const ushort4*>(t)[i];
    ushort4 fv = reinterpret_cast<const ushort4*>(featb)[i];
    float4 o;
    o.x = b2f(fv.x) + fmaxf(b2f(tv.x) * scale[d0 + 0] + shift[d0 + 0], 0.f);
    o.y = b2f(fv.y) + fmaxf(b2f(tv.y) * scale[d0 + 1] + shift[d0 + 1], 0.f);
    o.z = b2f(fv.z) + fmaxf(b2f(tv.z) * scale[d0 + 2] + shift[d0 + 2], 0.f);
    o.w = b2f(fv.w) + fmaxf(b2f(tv.w) * scale[d0 + 3] + shift[d0 + 3], 0.f);
    reinterpret_cast<float4*>(out)[i] = o;
}

extern "C" void kernel_launch(void* const* d_in, const int* in_sizes, int n_in,
                              void* d_out, int out_size, void* d_ws, size_t ws_size,
                              hipStream_t stream) {
    const float* feat  = (const float*)d_in[0];
    const float* snorm = (const float*)d_in[1];
    const float* W1    = (const float*)d_in[2];
    const float* W2    = (const float*)d_in[3];
    const float* W3    = (const float*)d_in[4];
    const float* bias  = (const float*)d_in[5];
    const float* gamma = (const float*)d_in[6];
    const float* beta  = (const float*)d_in[7];
    const int* esrc = (const int*)d_in[8];
    const int* edst = (const int*)d_in[9];
    float* out = (float*)d_out;

    char* ws = (char*)d_ws;
    ushort_t* t_bf    = (ushort_t*)(ws);                 // 12,800,000 (gemm output)
    int*      epos    = (int*)     (ws);                 //  3,200,000 ALIAS of t_bf
                                                         //  (epos dead before gemm_bn runs)
    ushort_t* feat_bf = (ushort_t*)(ws + 12800000);      // 12,800,000
    ushort_t* ax_bf   = (ushort_t*)(ws + 25600000);      // 12,800,000
    ushort_t* ax2_bf  = (ushort_t*)(ws + 38400000);      // 12,800,000
    int*      cnt_pad = (int*)     (ws + 38400000);      //  3,200,000 ALIAS of ax2_bf
                                                         //  (cnt_pad dead before gather#2 writes ax2_bf)
    int2*     csr     = (int2*)    (ws + 51200000);      //  6,400,000 (src, norm bits)
    float*    norm    = (float*)   (ws + 57600000);      //    200,000
    float*    gsums   = (float*)   (ws + 58000000);      //     16,384
    float*    gsq     = (float*)   (ws + 58016384);      //     16,384
    int*      off     = (int*)     (ws + 58032768);      //    200,064
    int*      part    = (int*)     (ws + 58232832);      //        512
    float*    scale   = (float*)   (ws + 58233856);      //        512
    float*    shift   = (float*)   (ws + 58234368);      //        512
    ushort_t* wcT     = (ushort_t*)(ws + 58234880);      //     98,304 (end 58,333,184)

    hipMemsetAsync(ws + 38400000, 0, 3200000, stream);   // cnt_pad (1 counter / 64B line)
    hipMemsetAsync(ws + 58000000, 0, 32768, stream);     // gsums, gsq

    epos_prep  <<<3125, 256, 0, stream>>>(edst, cnt_pad, epos, feat, feat_bf);
    scan_part  <<<SCAN_G, 512, 0, stream>>>(cnt_pad, part, norm);
    scan_final <<<SCAN_G + 96, 512, 0, stream>>>(cnt_pad, part, off, W1, W2, W3, wcT);
    fill_kernel<<<3125, 256, 0, stream>>>(esrc, edst, epos, off, norm, csr);

    gather_bf<<<3125, 256, 0, stream>>>(feat_bf, norm, off, csr, ax_bf);
    gather_bf<<<3125, 256, 0, stream>>>(ax_bf,   norm, off, csr, ax2_bf);

    gemm_bn<<<391, 256, 0, stream>>>(feat_bf, ax_bf, ax2_bf, wcT, bias, snorm,
                                     t_bf, gsums, gsq);
    bn_finalize<<<1, 128, 0, stream>>>(gsums, gsq, gamma, beta, scale, shift);
    epilogue   <<<6250, 256, 0, stream>>>(t_bf, feat_bf, scale, shift, out);
}